// Round 9
// baseline (1019.130 us; speedup 1.0000x reference)
//
#include <hip/hip_runtime.h>

// ECGNNEdgePredictor: 512 graphs x 30 nodes, HID=64, 5 NNConv layers + MLP head.
// One block per graph, 512 threads = 8 waves, 2 blocks/CU (grid-capped).
// R16 = R14's Y-scheme kernel VERBATIM (passed correctness, absmax 4.88e-4) with
// ONE change: __launch_bounds__(512, 2) instead of (512, 4).
// Root-cause insight: launch_bounds' 2nd arg = min WORKGROUPS/CU. (512,4) meant
// 4 blocks x 8 waves = 32 waves/CU = 8 waves/SIMD -> hard 64-VGPR cap. Every
// Y-scheme attempt (R8/R12/R14) spilled against MY OWN declared cap, not an
// allocator quirk. (512,2) -> 16 waves/CU target -> 128-VGPR budget; the grid
// caps us at 2 blocks/CU anyway, so occupancy is unchanged.
// Y-scheme per chunk: t = MFMA(hA,Ra,0); t = MFMA(hA,Rb,t); macc += z(f32)*t.
// Kills the 24 v_pk_mul_f16 + cvt per chunk (phase B's VALU bound since R7);
// z applied k-major on the C-side (za[r] <-> lane row q*4+r — R13's bug fixed).
// GATE: VGPR_Count must read >64 with FETCH/WRITE at MB scale. If it pegs 64
// and spills again, revert to R15 (143us gnn / 220us total, current best).

typedef float f32x4 __attribute__((ext_vector_type(4)));
typedef _Float16 f16x8 __attribute__((ext_vector_type(8)));

#define MFMA16(a, b, c) __builtin_amdgcn_mfma_f32_16x16x32_f16((a), (b), (c), 0, 0, 0)

// ws layout (bytes)
#define WS_W2S 0u         // 5*66*64*32 f16 = 1351680 B (W2 + b2 fused, B-frag order)
#define WS_W1S 1351680u   // 5*4*32*32  f16 = 40960 B
#define WS_WRS 1392640u   // 5*2*64*32  f16 = 40960 B
#define WS_BNS 1433600u   // 320 f32 scale
#define WS_BNH 1434880u   // 320 f32 shift
#define WS_WM1H 1436160u  // 4*64*32 f16 = 16384 B (Wm1 hi, B-frag order)
#define WS_WM1L 1452544u  // 16384 B (Wm1 lo)  -> end 1468928

__device__ inline f16x8 ld_frag_g(const _Float16* p) {
  union { uint4 u; f16x8 f; } c;
  c.u = *(const uint4*)p;
  return c.f;
}
__device__ inline f16x8 ld_frag_s(const _Float16* p) { return *(const f16x8*)p; }

// ---------------- prep (unchanged from R9) ----------------
__global__ __launch_bounds__(256) void prep_kernel(
    const float* __restrict__ W1, const float* __restrict__ W2,
    const float* __restrict__ b2, const float* __restrict__ Wr,
    const float* __restrict__ gamma, const float* __restrict__ beta,
    const float* __restrict__ rmean, const float* __restrict__ rvar,
    const float* __restrict__ Wm1, unsigned char* __restrict__ ws) {
  __shared__ __align__(16) float tile[32][68];
  const int tid = threadIdx.x;
  if (blockIdx.x < 330) {
    int l = blockIdx.x / 66, jb = blockIdx.x % 66;
    int s = tid >> 3, n0 = (tid & 7) * 8;
    int j = jb * 32 + s;
    const float* srcp = (j < 2048)
        ? (W2 + (size_t)l * 131072 + (size_t)j * 64 + n0)
        : (b2 + (size_t)l * 4096 + (size_t)(j - 2048) * 64 + n0);
    *(f32x4*)&tile[s][n0] = *(const f32x4*)srcp;
    *(f32x4*)&tile[s][n0 + 4] = *(const f32x4*)(srcp + 4);
    __syncthreads();
    int n = tid >> 2, sb = (tid & 3) * 8;
    f16x8 hv;
#pragma unroll
    for (int u = 0; u < 8; ++u) hv[u] = (_Float16)tile[sb + u][n];
    _Float16* dst = (_Float16*)(ws + WS_W2S) +
                    (size_t)l * 135168 + (size_t)jb * 2048 + n * 32 + sb;
    *(f16x8*)dst = hv;
    return;
  }
  int idx = (blockIdx.x - 330) * 256 + tid;
  _Float16* W1s = (_Float16*)(ws + WS_W1S);
  _Float16* Wrs = (_Float16*)(ws + WS_WRS);
  float* bns = (float*)(ws + WS_BNS);
  float* bnh = (float*)(ws + WS_BNH);
  _Float16* Wm1h = (_Float16*)(ws + WS_WM1H);
  _Float16* Wm1l = (_Float16*)(ws + WS_WM1L);
  if (idx < 20480) {            // W1s: K = 128
    int l = idx / 4096, r = idx % 4096;
    int t = r >> 10, n = (r >> 5) & 31, s2 = r & 31;
    int j = t * 32 + s2;
    W1s[idx] = (_Float16)W1[l * 4096 + j * 32 + n];
  } else if (idx < 40960) {     // Wrs: K = 64
    int i3 = idx - 20480;
    int l = i3 / 4096, r = i3 % 4096;
    int t = r >> 11, rem = r & 2047;
    int n = rem >> 5, s2 = rem & 31;
    int j = t * 32 + s2;
    Wrs[i3] = (_Float16)Wr[l * 4096 + j * 64 + n];
  } else if (idx < 41280) {     // BN folded
    int i4 = idx - 40960;
    float sc = gamma[i4] * rsqrtf(rvar[i4] + 1e-5f);
    bns[i4] = sc;
    bnh[i4] = beta[i4] - rmean[i4] * sc;
  } else if (idx < 49472) {     // Wm1 hi/lo: K = 128, N = 64
    int i5 = idx - 41280;
    int t = i5 >> 11, n = (i5 >> 5) & 63, s2 = i5 & 31;
    float w = Wm1[(t * 32 + s2) * 64 + n];
    _Float16 hi = (_Float16)w;
    Wm1h[i5] = hi;
    Wm1l[i5] = (_Float16)(w - (float)hi);
  }
}

// ---------------- main: one block per graph, 512 threads = 8 waves ----------------
// launch_bounds (512, 2): 2 workgroups/CU target = 16 waves/CU = 4 waves/SIMD
// -> 128-VGPR budget. The grid caps occupancy at 2 blocks/CU regardless.
__global__ __launch_bounds__(512, 2) void gnn_kernel(
    const float* __restrict__ x, const int* __restrict__ bu, const int* __restrict__ bv,
    const float* __restrict__ Wp, const float* __restrict__ bp,
    const float* __restrict__ b1, const float* __restrict__ brr,
    const float* __restrict__ bm1, const float* __restrict__ Wm2,
    const float* __restrict__ bm2,
    const _Float16* __restrict__ W2s, const _Float16* __restrict__ W1s,
    const _Float16* __restrict__ Wrs, const _Float16* __restrict__ Wm1h,
    const _Float16* __restrict__ Wm1l,
    const float* __restrict__ bns, const float* __restrict__ bnh,
    float* __restrict__ out) {
  __shared__ __align__(16) float hF[32][68];         // fp32 master h
  __shared__ __align__(16) _Float16 hH[32][72];      // f16 hi part of h
  __shared__ __align__(16) _Float16 hL[32][72];      // f16 lo part (h - hi)
  __shared__ __align__(16) float zT[32][100];        // z k-major: zT[k][e] (fp32)
  __shared__ __align__(16) float agg[32][68];        // scatter accumulator
  __shared__ int srcn[96], dstn[96];
  __shared__ float invdeg[32];

  const int tid = threadIdx.x;
  const int g = blockIdx.x;
  const int wv = tid >> 6;     // 0..7
  const int ln = tid & 63;
  const int q = ln >> 4;
  const int m16 = ln & 15;
  const f32x4 zero4 = {0.f, 0.f, 0.f, 0.f};
  float* const hidT = &zT[0][0];  // head reuse: [c*48 + e], 3072 <= 3200 floats

  // ---- init: edge lists (both directions), pad rows, agg zero
  if (tid < 96) {
    int s, d;
    if (tid < 41)      { s = bu[tid];      d = bv[tid]; }
    else if (tid < 82) { s = bv[tid - 41]; d = bu[tid - 41]; }
    else               { s = 0;            d = 0; }
    srcn[tid] = s; dstn[tid] = d;
  }
  if (tid < 136) { hF[30 + tid / 68][tid % 68] = 0.f; }
  if (tid < 144) {
    hH[30 + tid / 72][tid % 72] = (_Float16)0.f;
    hL[30 + tid / 72][tid % 72] = (_Float16)0.f;
  }
  for (int u = tid; u < 32 * 68; u += 512) ((float*)agg)[u] = 0.f;
  __syncthreads();
  if (tid < 32) {
    int cnt = 0;
    for (int e = 0; e < 82; ++e) cnt += (dstn[e] == tid) ? 1 : 0;
    invdeg[tid] = 1.0f / (float)(cnt > 0 ? cnt : 1);
  }
  // ---- projection h0 = x @ Wp + bp (fp32, then split hi/lo)
  for (int u = tid; u < 30 * 64; u += 512) {
    int n = u >> 6, c = u & 63;
    float acc = bp[c];
#pragma unroll
    for (int k = 0; k < 8; ++k) acc += x[(g * 30 + n) * 8 + k] * Wp[k * 64 + c];
    hF[n][c] = acc;
    _Float16 hi = (_Float16)acc;
    hH[n][c] = hi;
    hL[n][c] = (_Float16)(acc - (float)hi);
  }
  __syncthreads();

  for (int l = 0; l < 5; ++l) {
    // ======== phase A: root-GEMM (pre-update h) + z-GEMM -> zT (k-major) ========
    const int ncolR = (wv & 3) * 16 + m16;
    const int mtR = wv >> 2;
    float scl = bns[l * 64 + ncolR];
    float sft = bnh[l * 64 + ncolR];
    float brb = brr[l * 64 + ncolR];
    f32x4 racc = zero4;
    {
      f16x8 wb0 = ld_frag_g(Wrs + ((l * 2 + 0) * 64 + ncolR) * 32 + q * 8);
      f16x8 wb1 = ld_frag_g(Wrs + ((l * 2 + 1) * 64 + ncolR) * 32 + q * 8);
      racc = MFMA16(ld_frag_s(&hH[mtR * 16 + m16][q * 8]), wb0, racc);
      racc = MFMA16(ld_frag_s(&hH[mtR * 16 + m16][32 + q * 8]), wb1, racc);
      racc = MFMA16(ld_frag_s(&hL[mtR * 16 + m16][q * 8]), wb0, racc);
      racc = MFMA16(ld_frag_s(&hL[mtR * 16 + m16][32 + q * 8]), wb1, racc);
    }
    // z = relu([h_src|h_dst] @ W1 + b1): 12 tiles over 8 waves -> zT[k][e] (b128)
    {
      int ntz = wv & 1, g2 = wv >> 1;
      int ncol = ntz * 16 + m16;
      f16x8 bf[4];
#pragma unroll
      for (int t = 0; t < 4; ++t)
        bf[t] = ld_frag_g(W1s + ((l * 4 + t) * 32 + ncol) * 32 + q * 8);
      float b1v = b1[l * 32 + ncol];
#pragma unroll
      for (int mi = 0; mi < 2; ++mi) {
        int mt = g2 + mi * 4;
        if (mt < 6) {
          int e = mt * 16 + m16;
          int sn = srcn[e], dn = dstn[e];
          f32x4 acc = zero4;
#pragma unroll
          for (int t = 0; t < 4; ++t) {
            int nd = (t < 2) ? sn : dn;
            acc = MFMA16(ld_frag_s(&hH[nd][(t & 1) * 32 + q * 8]), bf[t], acc);
          }
#pragma unroll
          for (int t = 0; t < 4; ++t) {
            int nd = (t < 2) ? sn : dn;
            acc = MFMA16(ld_frag_s(&hL[nd][(t & 1) * 32 + q * 8]), bf[t], acc);
          }
          f32x4 zv;
#pragma unroll
          for (int r = 0; r < 4; ++r) zv[r] = fmaxf(acc[r] + b1v, 0.f);
          *(f32x4*)&zT[ncol][mt * 16 + (q << 2)] = zv;  // pads written, never scattered
        }
      }
    }
    __syncthreads();

    // ======== phase B: msg GEMM [96 x 2112] x [2112 x 64], Y-scheme ========
    // Wave w: N-cols [(w&3)*16,+16), M-half (w>>2). Bias chunk first (C-chain);
    // per chunk: t = hA @ W2chunk (2-MFMA chain, C=0), macc += zT[C][row] * t.
    // z is read k-major: za[r] scales this lane's C-row q*4+r.
    {
      int nt = wv & 3, mh = wv >> 2;
      int e0 = mh * 48 + m16, e1 = e0 + 16, e2 = e0 + 32;
      f16x8 hA[3][2];
      {
        int s0 = srcn[e0], s1 = srcn[e1], s2 = srcn[e2];
        hA[0][0] = ld_frag_s(&hH[s0][q * 8]); hA[0][1] = ld_frag_s(&hH[s0][32 + q * 8]);
        hA[1][0] = ld_frag_s(&hH[s1][q * 8]); hA[1][1] = ld_frag_s(&hH[s1][32 + q * 8]);
        hA[2][0] = ld_frag_s(&hH[s2][q * 8]); hA[2][1] = ld_frag_s(&hH[s2][32 + q * 8]);
      }
      f32x4 macc[3];
      const _Float16* Wb = W2s + (size_t)l * 135168 + (nt * 16 + m16) * 32 + q * 8;
      f16x8 r0a = ld_frag_g(Wb + (size_t)0 * 2048), r0b = ld_frag_g(Wb + (size_t)1 * 2048);
      f16x8 r1a = ld_frag_g(Wb + (size_t)2 * 2048), r1b = ld_frag_g(Wb + (size_t)3 * 2048);
      f16x8 r2a = ld_frag_g(Wb + (size_t)4 * 2048), r2b = ld_frag_g(Wb + (size_t)5 * 2048);
      f16x8 r3a, r3b;
      {
        f16x8 Bz0 = ld_frag_g(Wb + (size_t)64 * 2048), Bz1 = ld_frag_g(Wb + (size_t)65 * 2048);
        macc[0] = MFMA16(hA[0][0], Bz0, zero4); macc[0] = MFMA16(hA[0][1], Bz1, macc[0]);
        macc[1] = MFMA16(hA[1][0], Bz0, zero4); macc[1] = MFMA16(hA[1][1], Bz1, macc[1]);
        macc[2] = MFMA16(hA[2][0], Bz0, zero4); macc[2] = MFMA16(hA[2][1], Bz1, macc[2]);
      }
      const int eb0 = mh * 48 + (q << 2);
#define STEP(Ra, Rb, C) {                                                      \
        f32x4 za = *(const f32x4*)&zT[(C)][eb0];                               \
        f32x4 zb = *(const f32x4*)&zT[(C)][eb0 + 16];                          \
        f32x4 zc = *(const f32x4*)&zT[(C)][eb0 + 32];                          \
        f32x4 t0 = MFMA16(hA[0][0], Ra, zero4); t0 = MFMA16(hA[0][1], Rb, t0); \
        f32x4 t1 = MFMA16(hA[1][0], Ra, zero4); t1 = MFMA16(hA[1][1], Rb, t1); \
        f32x4 t2 = MFMA16(hA[2][0], Ra, zero4); t2 = MFMA16(hA[2][1], Rb, t2); \
        macc[0] += za * t0; macc[1] += zb * t1; macc[2] += zc * t2; }
      for (int cb = 0; cb < 32; cb += 4) {
        // unconditional ring prefetch; overread (past layer end at l=4)
        // stays inside ws (< 1468928 B) and is never consumed.
        r3a = ld_frag_g(Wb + (size_t)(2 * cb + 6) * 2048);
        r3b = ld_frag_g(Wb + (size_t)(2 * cb + 7) * 2048);
        STEP(r0a, r0b, cb + 0)
        r0a = ld_frag_g(Wb + (size_t)(2 * cb + 8) * 2048);
        r0b = ld_frag_g(Wb + (size_t)(2 * cb + 9) * 2048);
        STEP(r1a, r1b, cb + 1)
        r1a = ld_frag_g(Wb + (size_t)(2 * cb + 10) * 2048);
        r1b = ld_frag_g(Wb + (size_t)(2 * cb + 11) * 2048);
        STEP(r2a, r2b, cb + 2)
        r2a = ld_frag_g(Wb + (size_t)(2 * cb + 12) * 2048);
        r2b = ld_frag_g(Wb + (size_t)(2 * cb + 13) * 2048);
        STEP(r3a, r3b, cb + 3)
      }
#undef STEP
      // guarded scatter (pad edges e>=82 discarded)
#pragma unroll
      for (int mi = 0; mi < 3; ++mi) {
#pragma unroll
        for (int r = 0; r < 4; ++r) {
          int e = mh * 48 + mi * 16 + (q << 2) + r;
          if (e < 82) atomicAdd(&agg[dstn[e]][nt * 16 + m16], macc[mi][r]);
        }
      }
    }
    __syncthreads();

    // ======== phase C: h = relu(BN(agg/deg + racc + br)) + h ; re-zero agg ========
    {
#pragma unroll
      for (int r = 0; r < 4; ++r) {
        int row = mtR * 16 + (q << 2) + r;
        if (row < 30) {
          float v = agg[row][ncolR] * invdeg[row] + racc[r] + brb;
          agg[row][ncolR] = 0.f;
          v = v * scl + sft;
          float hn = fmaxf(v, 0.f) + hF[row][ncolR];
          hF[row][ncolR] = hn;
          _Float16 hi = (_Float16)hn;
          hH[row][ncolR] = hi;
          hL[row][ncolR] = (_Float16)(hn - (float)hi);
        }
      }
    }
    __syncthreads();
  }

  // ---- head: hid = relu([h_u|h_v] @ Wm1 + bm1) via MFMA (hi/lo x hi/lo, 3-term)
  {
    int nt = wv & 3, mtb = wv >> 2;
    int c = nt * 16 + m16;
    float bm1v = bm1[c];
    int nmt = (mtb == 0) ? 2 : 1;  // waves 0..3: mt {0,2}; waves 4..7: mt {1}
    for (int p2 = 0; p2 < nmt; ++p2) {
      int mt = (p2 == 0) ? mtb : 2;
      int e = mt * 16 + m16;       // rows 41..47 computed but discarded at stage 2
      int un = srcn[e], vn = dstn[e];
      f32x4 acc = zero4;
#pragma unroll
      for (int t = 0; t < 4; ++t) {
        int nd = (t < 2) ? un : vn;
        int co = (t & 1) * 32 + q * 8;
        f16x8 bh2 = ld_frag_g(Wm1h + (t * 64 + c) * 32 + q * 8);
        f16x8 bl2 = ld_frag_g(Wm1l + (t * 64 + c) * 32 + q * 8);
        f16x8 ah = ld_frag_s(&hH[nd][co]);
        f16x8 al = ld_frag_s(&hL[nd][co]);
        acc = MFMA16(ah, bh2, acc);
        acc = MFMA16(al, bh2, acc);
        acc = MFMA16(ah, bl2, acc);  // lo x lo dropped (~1e-6 rel)
      }
      f32x4 res;
#pragma unroll
      for (int r = 0; r < 4; ++r) res[r] = fmaxf(acc[r] + bm1v, 0.f);
      *(f32x4*)&hidT[c * 48 + mt * 16 + (q << 2)] = res;
    }
  }
  __syncthreads();
  if (tid < 41) {
    float acc = bm2[0];
#pragma unroll 4
    for (int c = 0; c < 64; ++c) acc += hidT[c * 48 + tid] * Wm2[c];
    out[g * 41 + tid] = acc;
  }
}

extern "C" void kernel_launch(void* const* d_in, const int* in_sizes, int n_in,
                              void* d_out, int out_size, void* d_ws, size_t ws_size,
                              hipStream_t stream) {
  const float* x   = (const float*)d_in[0];
  // d_in[1] = edge_index (rebuilt from branch lists), d_in[4] = num_graphs (const 512)
  const int* bu    = (const int*)d_in[2];
  const int* bv    = (const int*)d_in[3];
  const float* Wp  = (const float*)d_in[5];
  const float* bp  = (const float*)d_in[6];
  const float* W1  = (const float*)d_in[7];
  const float* b1  = (const float*)d_in[8];
  const float* W2  = (const float*)d_in[9];
  const float* b2  = (const float*)d_in[10];
  const float* Wr  = (const float*)d_in[11];
  const float* br  = (const float*)d_in[12];
  const float* gm  = (const float*)d_in[13];
  const float* bt  = (const float*)d_in[14];
  const float* rm  = (const float*)d_in[15];
  const float* rv  = (const float*)d_in[16];
  const float* Wm1 = (const float*)d_in[17];
  const float* bm1 = (const float*)d_in[18];
  const float* Wm2 = (const float*)d_in[19];
  const float* bm2 = (const float*)d_in[20];
  unsigned char* ws = (unsigned char*)d_ws;
  float* out = (float*)d_out;

  prep_kernel<<<524, 256, 0, stream>>>(W1, W2, b2, Wr, gm, bt, rm, rv, Wm1, ws);
  gnn_kernel<<<512, 512, 0, stream>>>(
      x, bu, bv, Wp, bp, b1, br, bm1, Wm2, bm2,
      (const _Float16*)(ws + WS_W2S),
      (const _Float16*)(ws + WS_W1S),
      (const _Float16*)(ws + WS_WRS),
      (const _Float16*)(ws + WS_WM1H),
      (const _Float16*)(ws + WS_WM1L),
      (const float*)(ws + WS_BNS),
      (const float*)(ws + WS_BNH),
      out);
}

// Round 10
// 259.444 us; speedup vs baseline: 3.9281x; 3.9281x over previous
//
#include <hip/hip_runtime.h>

// ECGNNEdgePredictor: 512 graphs x 30 nodes, HID=64, 5 NNConv layers + MLP head.
// One block per graph, 512 threads = 8 waves, 2 blocks/CU (grid-capped).
// R17 = R15 (best: 143us gnn / 220us total) + __launch_bounds__(512,2) +
// round-robin MFMA order in phase B (R12's STEP, now with registers to breathe).
// Ledger:
//  - launch_bounds 2nd arg = min WORKGROUPS/CU. (512,4) imposed a 64-VGPR cap;
//    (512,2) verified (R16) to unlock 128. Grid caps occupancy at 2 blocks/CU
//    regardless, and <=128 regs keeps 4 waves/SIMD -> occupancy unchanged.
//  - R12's round-robin (dep-distance 3 on macc chains, vs 1 for paired order)
//    was correct but spilled 47MB against the 64-cap -> 169us. Under the 128
//    budget its ~88-110 live regs fit. This is the experiment.
//  - Y-scheme: DEAD (R8/R13/R14/R16 — spills even at 128 regs).
//  - zEh f16 + z-group register prefetch: kept from R15 (proven +8us).
// GATE: WRITE_SIZE must stay MB-scale. If it balloons, revert to R15.

typedef float f32x4 __attribute__((ext_vector_type(4)));
typedef _Float16 f16x8 __attribute__((ext_vector_type(8)));
typedef _Float16 f16x4 __attribute__((ext_vector_type(4)));

#define MFMA16(a, b, c) __builtin_amdgcn_mfma_f32_16x16x32_f16((a), (b), (c), 0, 0, 0)

// ws layout (bytes)
#define WS_W2S 0u         // 5*66*64*32 f16 = 1351680 B (W2 + b2 fused, B-frag order)
#define WS_W1S 1351680u   // 5*4*32*32  f16 = 40960 B
#define WS_WRS 1392640u   // 5*2*64*32  f16 = 40960 B
#define WS_BNS 1433600u   // 320 f32 scale
#define WS_BNH 1434880u   // 320 f32 shift
#define WS_WM1H 1436160u  // 4*64*32 f16 = 16384 B (Wm1 hi, B-frag order)
#define WS_WM1L 1452544u  // 16384 B (Wm1 lo)  -> end 1468928

__device__ inline f16x8 ld_frag_g(const _Float16* p) {
  union { uint4 u; f16x8 f; } c;
  c.u = *(const uint4*)p;
  return c.f;
}
__device__ inline f16x8 ld_frag_s(const _Float16* p) { return *(const f16x8*)p; }

// ---------------- prep (unchanged from R9) ----------------
__global__ __launch_bounds__(256) void prep_kernel(
    const float* __restrict__ W1, const float* __restrict__ W2,
    const float* __restrict__ b2, const float* __restrict__ Wr,
    const float* __restrict__ gamma, const float* __restrict__ beta,
    const float* __restrict__ rmean, const float* __restrict__ rvar,
    const float* __restrict__ Wm1, unsigned char* __restrict__ ws) {
  __shared__ __align__(16) float tile[32][68];
  const int tid = threadIdx.x;
  if (blockIdx.x < 330) {
    int l = blockIdx.x / 66, jb = blockIdx.x % 66;
    int s = tid >> 3, n0 = (tid & 7) * 8;
    int j = jb * 32 + s;
    const float* srcp = (j < 2048)
        ? (W2 + (size_t)l * 131072 + (size_t)j * 64 + n0)
        : (b2 + (size_t)l * 4096 + (size_t)(j - 2048) * 64 + n0);
    *(f32x4*)&tile[s][n0] = *(const f32x4*)srcp;
    *(f32x4*)&tile[s][n0 + 4] = *(const f32x4*)(srcp + 4);
    __syncthreads();
    int n = tid >> 2, sb = (tid & 3) * 8;
    f16x8 hv;
#pragma unroll
    for (int u = 0; u < 8; ++u) hv[u] = (_Float16)tile[sb + u][n];
    _Float16* dst = (_Float16*)(ws + WS_W2S) +
                    (size_t)l * 135168 + (size_t)jb * 2048 + n * 32 + sb;
    *(f16x8*)dst = hv;
    return;
  }
  int idx = (blockIdx.x - 330) * 256 + tid;
  _Float16* W1s = (_Float16*)(ws + WS_W1S);
  _Float16* Wrs = (_Float16*)(ws + WS_WRS);
  float* bns = (float*)(ws + WS_BNS);
  float* bnh = (float*)(ws + WS_BNH);
  _Float16* Wm1h = (_Float16*)(ws + WS_WM1H);
  _Float16* Wm1l = (_Float16*)(ws + WS_WM1L);
  if (idx < 20480) {            // W1s: K = 128
    int l = idx / 4096, r = idx % 4096;
    int t = r >> 10, n = (r >> 5) & 31, s2 = r & 31;
    int j = t * 32 + s2;
    W1s[idx] = (_Float16)W1[l * 4096 + j * 32 + n];
  } else if (idx < 40960) {     // Wrs: K = 64
    int i3 = idx - 20480;
    int l = i3 / 4096, r = i3 % 4096;
    int t = r >> 11, rem = r & 2047;
    int n = rem >> 5, s2 = rem & 31;
    int j = t * 32 + s2;
    Wrs[i3] = (_Float16)Wr[l * 4096 + j * 64 + n];
  } else if (idx < 41280) {     // BN folded
    int i4 = idx - 40960;
    float sc = gamma[i4] * rsqrtf(rvar[i4] + 1e-5f);
    bns[i4] = sc;
    bnh[i4] = beta[i4] - rmean[i4] * sc;
  } else if (idx < 49472) {     // Wm1 hi/lo: K = 128, N = 64
    int i5 = idx - 41280;
    int t = i5 >> 11, n = (i5 >> 5) & 63, s2 = i5 & 31;
    float w = Wm1[(t * 32 + s2) * 64 + n];
    _Float16 hi = (_Float16)w;
    Wm1h[i5] = hi;
    Wm1l[i5] = (_Float16)(w - (float)hi);
  }
}

// ---------------- main: one block per graph, 512 threads = 8 waves ----------------
// (512, 2): 2 workgroups/CU = 16 waves/CU target -> 128-VGPR budget (verified R16).
__global__ __launch_bounds__(512, 2) void gnn_kernel(
    const float* __restrict__ x, const int* __restrict__ bu, const int* __restrict__ bv,
    const float* __restrict__ Wp, const float* __restrict__ bp,
    const float* __restrict__ b1, const float* __restrict__ brr,
    const float* __restrict__ bm1, const float* __restrict__ Wm2,
    const float* __restrict__ bm2,
    const _Float16* __restrict__ W2s, const _Float16* __restrict__ W1s,
    const _Float16* __restrict__ Wrs, const _Float16* __restrict__ Wm1h,
    const _Float16* __restrict__ Wm1l,
    const float* __restrict__ bns, const float* __restrict__ bnh,
    float* __restrict__ out) {
  __shared__ __align__(16) float hF[32][68];         // fp32 master h
  __shared__ __align__(16) _Float16 hH[32][72];      // f16 hi part of h
  __shared__ __align__(16) _Float16 hL[32][72];      // f16 lo part (h - hi)
  __shared__ __align__(16) _Float16 zEh[96][40];     // z edge-major [e][k], f16, padded
  __shared__ __align__(16) float agg[32][68];        // scatter accumulator
  __shared__ __align__(16) float hid2[64][48];       // head hidden [c][e]
  __shared__ int srcn[96], dstn[96];
  __shared__ float invdeg[32];

  const int tid = threadIdx.x;
  const int g = blockIdx.x;
  const int wv = tid >> 6;     // 0..7
  const int ln = tid & 63;
  const int q = ln >> 4;
  const int m16 = ln & 15;
  const f32x4 zero4 = {0.f, 0.f, 0.f, 0.f};

  // ---- init: edge lists (both directions), pad rows, agg zero
  if (tid < 96) {
    int s, d;
    if (tid < 41)      { s = bu[tid];      d = bv[tid]; }
    else if (tid < 82) { s = bv[tid - 41]; d = bu[tid - 41]; }
    else               { s = 0;            d = 0; }
    srcn[tid] = s; dstn[tid] = d;
  }
  if (tid < 136) { hF[30 + tid / 68][tid % 68] = 0.f; }
  if (tid < 144) {
    hH[30 + tid / 72][tid % 72] = (_Float16)0.f;
    hL[30 + tid / 72][tid % 72] = (_Float16)0.f;
  }
  for (int u = tid; u < 32 * 68; u += 512) ((float*)agg)[u] = 0.f;
  __syncthreads();
  if (tid < 32) {
    int cnt = 0;
    for (int e = 0; e < 82; ++e) cnt += (dstn[e] == tid) ? 1 : 0;
    invdeg[tid] = 1.0f / (float)(cnt > 0 ? cnt : 1);
  }
  // ---- projection h0 = x @ Wp + bp (fp32, then split hi/lo)
  for (int u = tid; u < 30 * 64; u += 512) {
    int n = u >> 6, c = u & 63;
    float acc = bp[c];
#pragma unroll
    for (int k = 0; k < 8; ++k) acc += x[(g * 30 + n) * 8 + k] * Wp[k * 64 + c];
    hF[n][c] = acc;
    _Float16 hi = (_Float16)acc;
    hH[n][c] = hi;
    hL[n][c] = (_Float16)(acc - (float)hi);
  }
  __syncthreads();

  for (int l = 0; l < 5; ++l) {
    // ======== phase A: root-GEMM (pre-update h) + z-GEMM ========
    const int ncolR = (wv & 3) * 16 + m16;
    const int mtR = wv >> 2;
    float scl = bns[l * 64 + ncolR];
    float sft = bnh[l * 64 + ncolR];
    float brb = brr[l * 64 + ncolR];
    f32x4 racc = zero4;
    {
      f16x8 wb0 = ld_frag_g(Wrs + ((l * 2 + 0) * 64 + ncolR) * 32 + q * 8);
      f16x8 wb1 = ld_frag_g(Wrs + ((l * 2 + 1) * 64 + ncolR) * 32 + q * 8);
      racc = MFMA16(ld_frag_s(&hH[mtR * 16 + m16][q * 8]), wb0, racc);
      racc = MFMA16(ld_frag_s(&hH[mtR * 16 + m16][32 + q * 8]), wb1, racc);
      racc = MFMA16(ld_frag_s(&hL[mtR * 16 + m16][q * 8]), wb0, racc);
      racc = MFMA16(ld_frag_s(&hL[mtR * 16 + m16][32 + q * 8]), wb1, racc);
    }
    // z = relu([h_src|h_dst] @ W1 + b1): 12 tiles over 8 waves -> zEh[e][k] (f16)
    {
      int ntz = wv & 1, g2 = wv >> 1;
      int ncol = ntz * 16 + m16;
      f16x8 bf[4];
#pragma unroll
      for (int t = 0; t < 4; ++t)
        bf[t] = ld_frag_g(W1s + ((l * 4 + t) * 32 + ncol) * 32 + q * 8);
      float b1v = b1[l * 32 + ncol];
#pragma unroll
      for (int mi = 0; mi < 2; ++mi) {
        int mt = g2 + mi * 4;
        if (mt < 6) {
          int e = mt * 16 + m16;
          int sn = srcn[e], dn = dstn[e];
          f32x4 acc = zero4;
#pragma unroll
          for (int t = 0; t < 4; ++t) {
            int nd = (t < 2) ? sn : dn;
            acc = MFMA16(ld_frag_s(&hH[nd][(t & 1) * 32 + q * 8]), bf[t], acc);
          }
#pragma unroll
          for (int t = 0; t < 4; ++t) {
            int nd = (t < 2) ? sn : dn;
            acc = MFMA16(ld_frag_s(&hL[nd][(t & 1) * 32 + q * 8]), bf[t], acc);
          }
#pragma unroll
          for (int r = 0; r < 4; ++r) {
            int e2 = mt * 16 + q * 4 + r;
            zEh[e2][ncol] = (_Float16)fmaxf(acc[r] + b1v, 0.f);  // pads never scattered
          }
        }
      }
    }
    __syncthreads();

    // ======== phase B: msg GEMM [96 x 2112] x [2112 x 64] ========
    // Wave w: N-cols [(w&3)*16,+16), M-half (w>>2). Bias chunk first; chunks
    // 0..31 with z (f16) folded into A; ring-4 W2 prefetch; z-group register
    // prefetch; ROUND-ROBIN MFMA order (macc dep-distance 3, was 1).
    {
      int nt = wv & 3, mh = wv >> 2;
      int e0 = mh * 48 + m16, e1 = e0 + 16, e2 = e0 + 32;
      f16x8 hA[3][2];
      {
        int s0 = srcn[e0], s1 = srcn[e1], s2 = srcn[e2];
        hA[0][0] = ld_frag_s(&hH[s0][q * 8]); hA[0][1] = ld_frag_s(&hH[s0][32 + q * 8]);
        hA[1][0] = ld_frag_s(&hH[s1][q * 8]); hA[1][1] = ld_frag_s(&hH[s1][32 + q * 8]);
        hA[2][0] = ld_frag_s(&hH[s2][q * 8]); hA[2][1] = ld_frag_s(&hH[s2][32 + q * 8]);
      }
      f32x4 macc[3] = {zero4, zero4, zero4};
      const _Float16* Wb = W2s + (size_t)l * 135168 + (nt * 16 + m16) * 32 + q * 8;
      f16x8 r0a = ld_frag_g(Wb + (size_t)0 * 2048), r0b = ld_frag_g(Wb + (size_t)1 * 2048);
      f16x8 r1a = ld_frag_g(Wb + (size_t)2 * 2048), r1b = ld_frag_g(Wb + (size_t)3 * 2048);
      f16x8 r2a = ld_frag_g(Wb + (size_t)4 * 2048), r2b = ld_frag_g(Wb + (size_t)5 * 2048);
      f16x8 r3a, r3b;
      f16x8 Bz0 = ld_frag_g(Wb + (size_t)64 * 2048), Bz1 = ld_frag_g(Wb + (size_t)65 * 2048);
      macc[0] = MFMA16(hA[0][0], Bz0, macc[0]);
      macc[1] = MFMA16(hA[1][0], Bz0, macc[1]);
      macc[2] = MFMA16(hA[2][0], Bz0, macc[2]);
      macc[0] = MFMA16(hA[0][1], Bz1, macc[0]);
      macc[1] = MFMA16(hA[1][1], Bz1, macc[1]);
      macc[2] = MFMA16(hA[2][1], Bz1, macc[2]);
      // z group 0 preload (f16x4 = ds_read_b64)
      f16x4 zc0 = *(const f16x4*)&zEh[e0][0];
      f16x4 zc1 = *(const f16x4*)&zEh[e1][0];
      f16x4 zc2 = *(const f16x4*)&zEh[e2][0];
#define STEP(Ra, Rb, P) {                                                    \
        _Float16 z0 = zb0[P], z1 = zb1[P], z2 = zb2[P];                      \
        f16x8 a00 = hA[0][0] * z0, a01 = hA[0][1] * z0;                      \
        f16x8 a10 = hA[1][0] * z1, a11 = hA[1][1] * z1;                      \
        f16x8 a20 = hA[2][0] * z2, a21 = hA[2][1] * z2;                      \
        macc[0] = MFMA16(a00, Ra, macc[0]);                                  \
        macc[1] = MFMA16(a10, Ra, macc[1]);                                  \
        macc[2] = MFMA16(a20, Ra, macc[2]);                                  \
        macc[0] = MFMA16(a01, Rb, macc[0]);                                  \
        macc[1] = MFMA16(a11, Rb, macc[1]);                                  \
        macc[2] = MFMA16(a21, Rb, macc[2]); }
      for (int cb = 0; cb < 32; cb += 4) {
        f16x4 zb0 = zc0, zb1 = zc1, zb2 = zc2;
        zc0 = *(const f16x4*)&zEh[e0][cb + 4];   // next-group prefetch (pad-safe)
        zc1 = *(const f16x4*)&zEh[e1][cb + 4];
        zc2 = *(const f16x4*)&zEh[e2][cb + 4];
        // unconditional ring prefetch; overread (past layer end at l=4)
        // stays inside ws (< 1468928 B) and is never consumed.
        r3a = ld_frag_g(Wb + (size_t)(2 * cb + 6) * 2048);
        r3b = ld_frag_g(Wb + (size_t)(2 * cb + 7) * 2048);
        STEP(r0a, r0b, 0)
        r0a = ld_frag_g(Wb + (size_t)(2 * cb + 8) * 2048);
        r0b = ld_frag_g(Wb + (size_t)(2 * cb + 9) * 2048);
        STEP(r1a, r1b, 1)
        r1a = ld_frag_g(Wb + (size_t)(2 * cb + 10) * 2048);
        r1b = ld_frag_g(Wb + (size_t)(2 * cb + 11) * 2048);
        STEP(r2a, r2b, 2)
        r2a = ld_frag_g(Wb + (size_t)(2 * cb + 12) * 2048);
        r2b = ld_frag_g(Wb + (size_t)(2 * cb + 13) * 2048);
        STEP(r3a, r3b, 3)
      }
#undef STEP
      // guarded scatter (pad edges e>=82 discarded)
#pragma unroll
      for (int mi = 0; mi < 3; ++mi) {
#pragma unroll
        for (int r = 0; r < 4; ++r) {
          int e = mh * 48 + mi * 16 + q * 4 + r;
          if (e < 82) atomicAdd(&agg[dstn[e]][nt * 16 + m16], macc[mi][r]);
        }
      }
    }
    __syncthreads();

    // ======== phase C: h = relu(BN(agg/deg + racc + br)) + h ; re-zero agg ========
    {
#pragma unroll
      for (int r = 0; r < 4; ++r) {
        int row = mtR * 16 + q * 4 + r;
        if (row < 30) {
          float v = agg[row][ncolR] * invdeg[row] + racc[r] + brb;
          agg[row][ncolR] = 0.f;
          v = v * scl + sft;
          float hn = fmaxf(v, 0.f) + hF[row][ncolR];
          hF[row][ncolR] = hn;
          _Float16 hi = (_Float16)hn;
          hH[row][ncolR] = hi;
          hL[row][ncolR] = (_Float16)(hn - (float)hi);
        }
      }
    }
    __syncthreads();
  }

  // ---- head: hid = relu([h_u|h_v] @ Wm1 + bm1) via MFMA (hi/lo x hi/lo, 3-term)
  {
    int nt = wv & 3, mtb = wv >> 2;
    int c = nt * 16 + m16;
    float bm1v = bm1[c];
    int nmt = (mtb == 0) ? 2 : 1;  // waves 0..3: mt {0,2}; waves 4..7: mt {1}
    for (int p2 = 0; p2 < nmt; ++p2) {
      int mt = (p2 == 0) ? mtb : 2;
      int e = mt * 16 + m16;       // rows 41..47 computed but discarded at stage 2
      int un = srcn[e], vn = dstn[e];
      f32x4 acc = zero4;
#pragma unroll
      for (int t = 0; t < 4; ++t) {
        int nd = (t < 2) ? un : vn;
        int co = (t & 1) * 32 + q * 8;
        f16x8 bh2 = ld_frag_g(Wm1h + (t * 64 + c) * 32 + q * 8);
        f16x8 bl2 = ld_frag_g(Wm1l + (t * 64 + c) * 32 + q * 8);
        f16x8 ah = ld_frag_s(&hH[nd][co]);
        f16x8 al = ld_frag_s(&hL[nd][co]);
        acc = MFMA16(ah, bh2, acc);
        acc = MFMA16(al, bh2, acc);
        acc = MFMA16(ah, bl2, acc);  // lo x lo dropped (~1e-6 rel)
      }
      f32x4 res;
#pragma unroll
      for (int r = 0; r < 4; ++r) res[r] = fmaxf(acc[r] + bm1v, 0.f);
      *(f32x4*)&hid2[c][mt * 16 + (q << 2)] = res;
    }
  }
  __syncthreads();
  if (tid < 41) {
    float acc = bm2[0];
#pragma unroll 4
    for (int c = 0; c < 64; ++c) acc += hid2[c][tid] * Wm2[c];
    out[g * 41 + tid] = acc;
  }
}

extern "C" void kernel_launch(void* const* d_in, const int* in_sizes, int n_in,
                              void* d_out, int out_size, void* d_ws, size_t ws_size,
                              hipStream_t stream) {
  const float* x   = (const float*)d_in[0];
  // d_in[1] = edge_index (rebuilt from branch lists), d_in[4] = num_graphs (const 512)
  const int* bu    = (const int*)d_in[2];
  const int* bv    = (const int*)d_in[3];
  const float* Wp  = (const float*)d_in[5];
  const float* bp  = (const float*)d_in[6];
  const float* W1  = (const float*)d_in[7];
  const float* b1  = (const float*)d_in[8];
  const float* W2  = (const float*)d_in[9];
  const float* b2  = (const float*)d_in[10];
  const float* Wr  = (const float*)d_in[11];
  const float* br  = (const float*)d_in[12];
  const float* gm  = (const float*)d_in[13];
  const float* bt  = (const float*)d_in[14];
  const float* rm  = (const float*)d_in[15];
  const float* rv  = (const float*)d_in[16];
  const float* Wm1 = (const float*)d_in[17];
  const float* bm1 = (const float*)d_in[18];
  const float* Wm2 = (const float*)d_in[19];
  const float* bm2 = (const float*)d_in[20];
  unsigned char* ws = (unsigned char*)d_ws;
  float* out = (float*)d_out;

  prep_kernel<<<524, 256, 0, stream>>>(W1, W2, b2, Wr, gm, bt, rm, rv, Wm1, ws);
  gnn_kernel<<<512, 512, 0, stream>>>(
      x, bu, bv, Wp, bp, b1, br, bm1, Wm2, bm2,
      (const _Float16*)(ws + WS_W2S),
      (const _Float16*)(ws + WS_W1S),
      (const _Float16*)(ws + WS_WRS),
      (const _Float16*)(ws + WS_WM1H),
      (const _Float16*)(ws + WS_WM1L),
      (const float*)(ws + WS_BNS),
      (const float*)(ws + WS_BNH),
      out);
}

// Round 12
// 219.671 us; speedup vs baseline: 4.6393x; 1.1811x over previous
//
#include <hip/hip_runtime.h>

// ECGNNEdgePredictor: 512 graphs x 30 nodes, HID=64, 5 NNConv layers + MLP head.
// One block per graph, 512 threads = 8 waves, 2 blocks/CU (grid-capped).
// R18 (resubmit — previous attempt died to a container infra failure, no data)
// = R15 (best: 143.4us gnn / 220us total) + three register-neutral fixes:
//  - root folded into agg: phase A stores agg[row][col] = racc*deg[row] (plain
//    store, one writer/cell); B atomics add msgs; C does agg*invdeg + br.
//    (msg + root*deg)/deg == msg/deg + root, deg clamped >=1 like invdeg.
//    Kills racc cross-phase liveness, the C re-zero, and the init agg-zero.
//  - phase A balanced: waves 0-5 do 2 z-tiles (16 MFMA); waves 6-7 sweep all
//    8 root tiles sequentially (16 MFMA). Was 20 vs 12.
//  - zEh stride 40 -> 36 f16: stride-40 write was a 4-way bank conflict
//    (q, q+2 collide); stride-36 spreads (q, m16/2) over all 32 banks.
// Empirical law (R15/R16/R17): <=64 VGPR -> 2 blocks/CU; >64 -> 1 block/CU
// (halved occupancy, lost 40us). GATE: VGPR_Count must stay 64.
// Y-scheme: DEAD (4 attempts). 1024-thread shapes: DEAD. launch_bounds(512,4).

typedef float f32x4 __attribute__((ext_vector_type(4)));
typedef _Float16 f16x8 __attribute__((ext_vector_type(8)));
typedef _Float16 f16x4 __attribute__((ext_vector_type(4)));

#define MFMA16(a, b, c) __builtin_amdgcn_mfma_f32_16x16x32_f16((a), (b), (c), 0, 0, 0)

// ws layout (bytes)
#define WS_W2S 0u         // 5*66*64*32 f16 = 1351680 B (W2 + b2 fused, B-frag order)
#define WS_W1S 1351680u   // 5*4*32*32  f16 = 40960 B
#define WS_WRS 1392640u   // 5*2*64*32  f16 = 40960 B
#define WS_BNS 1433600u   // 320 f32 scale
#define WS_BNH 1434880u   // 320 f32 shift
#define WS_WM1H 1436160u  // 4*64*32 f16 = 16384 B (Wm1 hi, B-frag order)
#define WS_WM1L 1452544u  // 16384 B (Wm1 lo)  -> end 1468928

__device__ inline f16x8 ld_frag_g(const _Float16* p) {
  union { uint4 u; f16x8 f; } c;
  c.u = *(const uint4*)p;
  return c.f;
}
__device__ inline f16x8 ld_frag_s(const _Float16* p) { return *(const f16x8*)p; }

// ---------------- prep (unchanged from R9) ----------------
__global__ __launch_bounds__(256) void prep_kernel(
    const float* __restrict__ W1, const float* __restrict__ W2,
    const float* __restrict__ b2, const float* __restrict__ Wr,
    const float* __restrict__ gamma, const float* __restrict__ beta,
    const float* __restrict__ rmean, const float* __restrict__ rvar,
    const float* __restrict__ Wm1, unsigned char* __restrict__ ws) {
  __shared__ __align__(16) float tile[32][68];
  const int tid = threadIdx.x;
  if (blockIdx.x < 330) {
    int l = blockIdx.x / 66, jb = blockIdx.x % 66;
    int s = tid >> 3, n0 = (tid & 7) * 8;
    int j = jb * 32 + s;
    const float* srcp = (j < 2048)
        ? (W2 + (size_t)l * 131072 + (size_t)j * 64 + n0)
        : (b2 + (size_t)l * 4096 + (size_t)(j - 2048) * 64 + n0);
    *(f32x4*)&tile[s][n0] = *(const f32x4*)srcp;
    *(f32x4*)&tile[s][n0 + 4] = *(const f32x4*)(srcp + 4);
    __syncthreads();
    int n = tid >> 2, sb = (tid & 3) * 8;
    f16x8 hv;
#pragma unroll
    for (int u = 0; u < 8; ++u) hv[u] = (_Float16)tile[sb + u][n];
    _Float16* dst = (_Float16*)(ws + WS_W2S) +
                    (size_t)l * 135168 + (size_t)jb * 2048 + n * 32 + sb;
    *(f16x8*)dst = hv;
    return;
  }
  int idx = (blockIdx.x - 330) * 256 + tid;
  _Float16* W1s = (_Float16*)(ws + WS_W1S);
  _Float16* Wrs = (_Float16*)(ws + WS_WRS);
  float* bns = (float*)(ws + WS_BNS);
  float* bnh = (float*)(ws + WS_BNH);
  _Float16* Wm1h = (_Float16*)(ws + WS_WM1H);
  _Float16* Wm1l = (_Float16*)(ws + WS_WM1L);
  if (idx < 20480) {            // W1s: K = 128
    int l = idx / 4096, r = idx % 4096;
    int t = r >> 10, n = (r >> 5) & 31, s2 = r & 31;
    int j = t * 32 + s2;
    W1s[idx] = (_Float16)W1[l * 4096 + j * 32 + n];
  } else if (idx < 40960) {     // Wrs: K = 64
    int i3 = idx - 20480;
    int l = i3 / 4096, r = i3 % 4096;
    int t = r >> 11, rem = r & 2047;
    int n = rem >> 5, s2 = rem & 31;
    int j = t * 32 + s2;
    Wrs[i3] = (_Float16)Wr[l * 4096 + j * 64 + n];
  } else if (idx < 41280) {     // BN folded
    int i4 = idx - 40960;
    float sc = gamma[i4] * rsqrtf(rvar[i4] + 1e-5f);
    bns[i4] = sc;
    bnh[i4] = beta[i4] - rmean[i4] * sc;
  } else if (idx < 49472) {     // Wm1 hi/lo: K = 128, N = 64
    int i5 = idx - 41280;
    int t = i5 >> 11, n = (i5 >> 5) & 63, s2 = i5 & 31;
    float w = Wm1[(t * 32 + s2) * 64 + n];
    _Float16 hi = (_Float16)w;
    Wm1h[i5] = hi;
    Wm1l[i5] = (_Float16)(w - (float)hi);
  }
}

// ---------------- main: one block per graph, 512 threads = 8 waves ----------------
__global__ __launch_bounds__(512, 4) void gnn_kernel(
    const float* __restrict__ x, const int* __restrict__ bu, const int* __restrict__ bv,
    const float* __restrict__ Wp, const float* __restrict__ bp,
    const float* __restrict__ b1, const float* __restrict__ brr,
    const float* __restrict__ bm1, const float* __restrict__ Wm2,
    const float* __restrict__ bm2,
    const _Float16* __restrict__ W2s, const _Float16* __restrict__ W1s,
    const _Float16* __restrict__ Wrs, const _Float16* __restrict__ Wm1h,
    const _Float16* __restrict__ Wm1l,
    const float* __restrict__ bns, const float* __restrict__ bnh,
    float* __restrict__ out) {
  __shared__ __align__(16) float hF[32][68];         // fp32 master h
  __shared__ __align__(16) _Float16 hH[32][72];      // f16 hi part of h
  __shared__ __align__(16) _Float16 hL[32][72];      // f16 lo part (h - hi)
  __shared__ __align__(16) _Float16 zEh[96][36];     // z edge-major [e][k], f16, pad 4
  __shared__ __align__(16) float agg[32][68];        // root*deg + msg accumulator
  __shared__ __align__(16) float hid2[64][48];       // head hidden [c][e]
  __shared__ int srcn[96], dstn[96];
  __shared__ float invdeg[32];
  __shared__ float degf[32];

  const int tid = threadIdx.x;
  const int g = blockIdx.x;
  const int wv = tid >> 6;     // 0..7
  const int ln = tid & 63;
  const int q = ln >> 4;
  const int m16 = ln & 15;
  const f32x4 zero4 = {0.f, 0.f, 0.f, 0.f};

  // ---- init: edge lists (both directions), pad rows (no agg init needed:
  // phase A plain-stores every agg row 0..31 each layer)
  if (tid < 96) {
    int s, d;
    if (tid < 41)      { s = bu[tid];      d = bv[tid]; }
    else if (tid < 82) { s = bv[tid - 41]; d = bu[tid - 41]; }
    else               { s = 0;            d = 0; }
    srcn[tid] = s; dstn[tid] = d;
  }
  if (tid < 136) { hF[30 + tid / 68][tid % 68] = 0.f; }
  if (tid < 144) {
    hH[30 + tid / 72][tid % 72] = (_Float16)0.f;
    hL[30 + tid / 72][tid % 72] = (_Float16)0.f;
  }
  __syncthreads();
  if (tid < 32) {
    int cnt = 0;
    for (int e = 0; e < 82; ++e) cnt += (dstn[e] == tid) ? 1 : 0;
    int c1 = (cnt > 0) ? cnt : 1;
    invdeg[tid] = 1.0f / (float)c1;
    degf[tid] = (float)c1;   // matches the invdeg clamp: (msg+root*deg)/deg
  }
  // ---- projection h0 = x @ Wp + bp (fp32, then split hi/lo)
  for (int u = tid; u < 30 * 64; u += 512) {
    int n = u >> 6, c = u & 63;
    float acc = bp[c];
#pragma unroll
    for (int k = 0; k < 8; ++k) acc += x[(g * 30 + n) * 8 + k] * Wp[k * 64 + c];
    hF[n][c] = acc;
    _Float16 hi = (_Float16)acc;
    hH[n][c] = hi;
    hL[n][c] = (_Float16)(acc - (float)hi);
  }
  __syncthreads();   // also orders degf writes before phase-A reads

  for (int l = 0; l < 5; ++l) {
    // ======== phase A (balanced 16 MFMA/wave) ========
    // waves 0..5: two z-tiles each; waves 6..7: all 8 root tiles -> agg.
    if (wv < 6) {
      // z = relu([h_src|h_dst] @ W1 + b1) -> zEh[e][k] (f16)
      int ntz = (wv >= 3) ? 1 : 0;
      int mtb = (wv % 3) * 2;
      int ncol = ntz * 16 + m16;
      f16x8 bf[4];
#pragma unroll
      for (int t = 0; t < 4; ++t)
        bf[t] = ld_frag_g(W1s + ((l * 4 + t) * 32 + ncol) * 32 + q * 8);
      float b1v = b1[l * 32 + ncol];
#pragma unroll
      for (int mi = 0; mi < 2; ++mi) {
        int mt = mtb + mi;
        int e = mt * 16 + m16;
        int sn = srcn[e], dn = dstn[e];
        f32x4 acc = zero4;
#pragma unroll
        for (int t = 0; t < 4; ++t) {
          int nd = (t < 2) ? sn : dn;
          acc = MFMA16(ld_frag_s(&hH[nd][(t & 1) * 32 + q * 8]), bf[t], acc);
        }
#pragma unroll
        for (int t = 0; t < 4; ++t) {
          int nd = (t < 2) ? sn : dn;
          acc = MFMA16(ld_frag_s(&hL[nd][(t & 1) * 32 + q * 8]), bf[t], acc);
        }
#pragma unroll
        for (int r = 0; r < 4; ++r) {
          int e2 = mt * 16 + q * 4 + r;
          zEh[e2][ncol] = (_Float16)fmaxf(acc[r] + b1v, 0.f);  // pads never scattered
        }
      }
    } else {
      // root-GEMM: agg[row][col] = (h @ Wr)[row][col] * deg[row] (plain store)
#pragma unroll
      for (int nq = 0; nq < 2; ++nq) {
        int ncolR = ((wv - 6) * 2 + nq) * 16 + m16;
        f16x8 wb0 = ld_frag_g(Wrs + ((l * 2 + 0) * 64 + ncolR) * 32 + q * 8);
        f16x8 wb1 = ld_frag_g(Wrs + ((l * 2 + 1) * 64 + ncolR) * 32 + q * 8);
#pragma unroll
        for (int mtR = 0; mtR < 2; ++mtR) {
          f32x4 racc = zero4;
          racc = MFMA16(ld_frag_s(&hH[mtR * 16 + m16][q * 8]), wb0, racc);
          racc = MFMA16(ld_frag_s(&hH[mtR * 16 + m16][32 + q * 8]), wb1, racc);
          racc = MFMA16(ld_frag_s(&hL[mtR * 16 + m16][q * 8]), wb0, racc);
          racc = MFMA16(ld_frag_s(&hL[mtR * 16 + m16][32 + q * 8]), wb1, racc);
#pragma unroll
          for (int r = 0; r < 4; ++r) {
            int row = mtR * 16 + q * 4 + r;
            agg[row][ncolR] = racc[r] * degf[row & 31];
          }
        }
      }
    }
    __syncthreads();

    // ======== phase B: msg GEMM [96 x 2112] x [2112 x 64] (R15 verbatim) ========
    {
      int nt = wv & 3, mh = wv >> 2;
      int e0 = mh * 48 + m16, e1 = e0 + 16, e2 = e0 + 32;
      f16x8 hA[3][2];
      {
        int s0 = srcn[e0], s1 = srcn[e1], s2 = srcn[e2];
        hA[0][0] = ld_frag_s(&hH[s0][q * 8]); hA[0][1] = ld_frag_s(&hH[s0][32 + q * 8]);
        hA[1][0] = ld_frag_s(&hH[s1][q * 8]); hA[1][1] = ld_frag_s(&hH[s1][32 + q * 8]);
        hA[2][0] = ld_frag_s(&hH[s2][q * 8]); hA[2][1] = ld_frag_s(&hH[s2][32 + q * 8]);
      }
      f32x4 macc[3] = {zero4, zero4, zero4};
      const _Float16* Wb = W2s + (size_t)l * 135168 + (nt * 16 + m16) * 32 + q * 8;
      f16x8 r0a = ld_frag_g(Wb + (size_t)0 * 2048), r0b = ld_frag_g(Wb + (size_t)1 * 2048);
      f16x8 r1a = ld_frag_g(Wb + (size_t)2 * 2048), r1b = ld_frag_g(Wb + (size_t)3 * 2048);
      f16x8 r2a = ld_frag_g(Wb + (size_t)4 * 2048), r2b = ld_frag_g(Wb + (size_t)5 * 2048);
      f16x8 r3a, r3b;
      f16x8 Bz0 = ld_frag_g(Wb + (size_t)64 * 2048), Bz1 = ld_frag_g(Wb + (size_t)65 * 2048);
      macc[0] = MFMA16(hA[0][0], Bz0, macc[0]); macc[0] = MFMA16(hA[0][1], Bz1, macc[0]);
      macc[1] = MFMA16(hA[1][0], Bz0, macc[1]); macc[1] = MFMA16(hA[1][1], Bz1, macc[1]);
      macc[2] = MFMA16(hA[2][0], Bz0, macc[2]); macc[2] = MFMA16(hA[2][1], Bz1, macc[2]);
      // z group 0 preload (f16x4 = ds_read_b64)
      f16x4 zc0 = *(const f16x4*)&zEh[e0][0];
      f16x4 zc1 = *(const f16x4*)&zEh[e1][0];
      f16x4 zc2 = *(const f16x4*)&zEh[e2][0];
      for (int cb = 0; cb < 32; cb += 4) {
        f16x4 zb0 = zc0, zb1 = zc1, zb2 = zc2;
        zc0 = *(const f16x4*)&zEh[e0][cb + 4];   // next-group prefetch (pad-safe)
        zc1 = *(const f16x4*)&zEh[e1][cb + 4];
        zc2 = *(const f16x4*)&zEh[e2][cb + 4];
        // unconditional ring prefetch; overread (past layer end at l=4)
        // stays inside ws (< 1468928 B) and is never consumed.
        { // p=0: use slot0 (cb), prefetch cb+3 -> slot3
          r3a = ld_frag_g(Wb + (size_t)(2 * cb + 6) * 2048);
          r3b = ld_frag_g(Wb + (size_t)(2 * cb + 7) * 2048);
          _Float16 z0 = zb0[0], z1 = zb1[0], z2 = zb2[0];
          macc[0] = MFMA16(hA[0][0] * z0, r0a, macc[0]); macc[0] = MFMA16(hA[0][1] * z0, r0b, macc[0]);
          macc[1] = MFMA16(hA[1][0] * z1, r0a, macc[1]); macc[1] = MFMA16(hA[1][1] * z1, r0b, macc[1]);
          macc[2] = MFMA16(hA[2][0] * z2, r0a, macc[2]); macc[2] = MFMA16(hA[2][1] * z2, r0b, macc[2]);
        }
        { // p=1: use slot1 (cb+1), prefetch cb+4 -> slot0
          r0a = ld_frag_g(Wb + (size_t)(2 * cb + 8) * 2048);
          r0b = ld_frag_g(Wb + (size_t)(2 * cb + 9) * 2048);
          _Float16 z0 = zb0[1], z1 = zb1[1], z2 = zb2[1];
          macc[0] = MFMA16(hA[0][0] * z0, r1a, macc[0]); macc[0] = MFMA16(hA[0][1] * z0, r1b, macc[0]);
          macc[1] = MFMA16(hA[1][0] * z1, r1a, macc[1]); macc[1] = MFMA16(hA[1][1] * z1, r1b, macc[1]);
          macc[2] = MFMA16(hA[2][0] * z2, r1a, macc[2]); macc[2] = MFMA16(hA[2][1] * z2, r1b, macc[2]);
        }
        { // p=2: use slot2 (cb+2), prefetch cb+5 -> slot1
          r1a = ld_frag_g(Wb + (size_t)(2 * cb + 10) * 2048);
          r1b = ld_frag_g(Wb + (size_t)(2 * cb + 11) * 2048);
          _Float16 z0 = zb0[2], z1 = zb1[2], z2 = zb2[2];
          macc[0] = MFMA16(hA[0][0] * z0, r2a, macc[0]); macc[0] = MFMA16(hA[0][1] * z0, r2b, macc[0]);
          macc[1] = MFMA16(hA[1][0] * z1, r2a, macc[1]); macc[1] = MFMA16(hA[1][1] * z1, r2b, macc[1]);
          macc[2] = MFMA16(hA[2][0] * z2, r2a, macc[2]); macc[2] = MFMA16(hA[2][1] * z2, r2b, macc[2]);
        }
        { // p=3: use slot3 (cb+3), prefetch cb+6 -> slot2
          r2a = ld_frag_g(Wb + (size_t)(2 * cb + 12) * 2048);
          r2b = ld_frag_g(Wb + (size_t)(2 * cb + 13) * 2048);
          _Float16 z0 = zb0[3], z1 = zb1[3], z2 = zb2[3];
          macc[0] = MFMA16(hA[0][0] * z0, r3a, macc[0]); macc[0] = MFMA16(hA[0][1] * z0, r3b, macc[0]);
          macc[1] = MFMA16(hA[1][0] * z1, r3a, macc[1]); macc[1] = MFMA16(hA[1][1] * z1, r3b, macc[1]);
          macc[2] = MFMA16(hA[2][0] * z2, r3a, macc[2]); macc[2] = MFMA16(hA[2][1] * z2, r3b, macc[2]);
        }
      }
      // guarded scatter (pad edges e>=82 discarded)
#pragma unroll
      for (int mi = 0; mi < 3; ++mi) {
#pragma unroll
        for (int r = 0; r < 4; ++r) {
          int e = mh * 48 + mi * 16 + q * 4 + r;
          if (e < 82) atomicAdd(&agg[dstn[e]][nt * 16 + m16], macc[mi][r]);
        }
      }
    }
    __syncthreads();

    // ======== phase C: h = relu(BN(agg*invdeg + br)) + h (root inside agg) ========
    {
      const int ncolC = (wv & 3) * 16 + m16;
      const int mtC = wv >> 2;
      float scl = bns[l * 64 + ncolC];
      float sft = bnh[l * 64 + ncolC];
      float brb = brr[l * 64 + ncolC];
#pragma unroll
      for (int r = 0; r < 4; ++r) {
        int row = mtC * 16 + q * 4 + r;
        if (row < 30) {
          float v = agg[row][ncolC] * invdeg[row] + brb;
          v = v * scl + sft;
          float hn = fmaxf(v, 0.f) + hF[row][ncolC];
          hF[row][ncolC] = hn;
          _Float16 hi = (_Float16)hn;
          hH[row][ncolC] = hi;
          hL[row][ncolC] = (_Float16)(hn - (float)hi);
        }
      }
    }
    __syncthreads();
  }

  // ---- head: hid = relu([h_u|h_v] @ Wm1 + bm1) via MFMA (hi/lo x hi/lo, 3-term)
  {
    int nt = wv & 3, mtb = wv >> 2;
    int c = nt * 16 + m16;
    float bm1v = bm1[c];
    int nmt = (mtb == 0) ? 2 : 1;  // waves 0..3: mt {0,2}; waves 4..7: mt {1}
    for (int p2 = 0; p2 < nmt; ++p2) {
      int mt = (p2 == 0) ? mtb : 2;
      int e = mt * 16 + m16;       // rows 41..47 computed but discarded at stage 2
      int un = srcn[e], vn = dstn[e];
      f32x4 acc = zero4;
#pragma unroll
      for (int t = 0; t < 4; ++t) {
        int nd = (t < 2) ? un : vn;
        int co = (t & 1) * 32 + q * 8;
        f16x8 bh2 = ld_frag_g(Wm1h + (t * 64 + c) * 32 + q * 8);
        f16x8 bl2 = ld_frag_g(Wm1l + (t * 64 + c) * 32 + q * 8);
        f16x8 ah = ld_frag_s(&hH[nd][co]);
        f16x8 al = ld_frag_s(&hL[nd][co]);
        acc = MFMA16(ah, bh2, acc);
        acc = MFMA16(al, bh2, acc);
        acc = MFMA16(ah, bl2, acc);  // lo x lo dropped (~1e-6 rel)
      }
      f32x4 res;
#pragma unroll
      for (int r = 0; r < 4; ++r) res[r] = fmaxf(acc[r] + bm1v, 0.f);
      *(f32x4*)&hid2[c][mt * 16 + (q << 2)] = res;
    }
  }
  __syncthreads();
  if (tid < 41) {
    float acc = bm2[0];
#pragma unroll 4
    for (int c = 0; c < 64; ++c) acc += hid2[c][tid] * Wm2[c];
    out[g * 41 + tid] = acc;
  }
}

extern "C" void kernel_launch(void* const* d_in, const int* in_sizes, int n_in,
                              void* d_out, int out_size, void* d_ws, size_t ws_size,
                              hipStream_t stream) {
  const float* x   = (const float*)d_in[0];
  // d_in[1] = edge_index (rebuilt from branch lists), d_in[4] = num_graphs (const 512)
  const int* bu    = (const int*)d_in[2];
  const int* bv    = (const int*)d_in[3];
  const float* Wp  = (const float*)d_in[5];
  const float* bp  = (const float*)d_in[6];
  const float* W1  = (const float*)d_in[7];
  const float* b1  = (const float*)d_in[8];
  const float* W2  = (const float*)d_in[9];
  const float* b2  = (const float*)d_in[10];
  const float* Wr  = (const float*)d_in[11];
  const float* br  = (const float*)d_in[12];
  const float* gm  = (const float*)d_in[13];
  const float* bt  = (const float*)d_in[14];
  const float* rm  = (const float*)d_in[15];
  const float* rv  = (const float*)d_in[16];
  const float* Wm1 = (const float*)d_in[17];
  const float* bm1 = (const float*)d_in[18];
  const float* Wm2 = (const float*)d_in[19];
  const float* bm2 = (const float*)d_in[20];
  unsigned char* ws = (unsigned char*)d_ws;
  float* out = (float*)d_out;

  prep_kernel<<<524, 256, 0, stream>>>(W1, W2, b2, Wr, gm, bt, rm, rv, Wm1, ws);
  gnn_kernel<<<512, 512, 0, stream>>>(
      x, bu, bv, Wp, bp, b1, br, bm1, Wm2, bm2,
      (const _Float16*)(ws + WS_W2S),
      (const _Float16*)(ws + WS_W1S),
      (const _Float16*)(ws + WS_WRS),
      (const _Float16*)(ws + WS_WM1H),
      (const _Float16*)(ws + WS_WM1L),
      (const float*)(ws + WS_BNS),
      (const float*)(ws + WS_BNH),
      out);
}

// Round 13
// 219.214 us; speedup vs baseline: 4.6490x; 1.0021x over previous
//
#include <hip/hip_runtime.h>

// ECGNNEdgePredictor: 512 graphs x 30 nodes, HID=64, 5 NNConv layers + MLP head.
// One block per graph, 512 threads = 8 waves, 2 blocks/CU (grid-capped).
// R19 = R18 (219.7us total / 143.5us gnn, best) + two free trims:
//  - projection x reads vectorized (2x float4 vs 8 scalar loads per element)
//  - phase-B prologue issues Bz0/Bz1 FIRST (consumed first by bias MFMAs)
// Constraint laws established this session (all falsified experimentally):
//  - <=64 VGPR -> 2 blocks/CU; >64 -> 1 block/CU (R16/R17: 80 regs = 22% occ).
//  - Y-scheme (macc out of MFMA C-chain) spills at any register cap (R8/13/14/16).
//  - 1024-thread shapes lose (R10/R11); round-robin MFMA order loses (R17).
//  - Work deletion / bank-conflict fixes are NEUTRAL (R18): kernel is
//    latency-structural: ~33K cy/layer/SIMD of L2-burst + 3 barrier drains,
//    with MFMA floor 11.6K and VALU 20K overlapped beneath.
// Remaining known lever: inline-asm counted-vmcnt W2 LDS staging (T3/T4) —
// high-risk, compiler-hostile, negative EV after 6 structural regressions.

typedef float f32x4 __attribute__((ext_vector_type(4)));
typedef _Float16 f16x8 __attribute__((ext_vector_type(8)));
typedef _Float16 f16x4 __attribute__((ext_vector_type(4)));

#define MFMA16(a, b, c) __builtin_amdgcn_mfma_f32_16x16x32_f16((a), (b), (c), 0, 0, 0)

// ws layout (bytes)
#define WS_W2S 0u         // 5*66*64*32 f16 = 1351680 B (W2 + b2 fused, B-frag order)
#define WS_W1S 1351680u   // 5*4*32*32  f16 = 40960 B
#define WS_WRS 1392640u   // 5*2*64*32  f16 = 40960 B
#define WS_BNS 1433600u   // 320 f32 scale
#define WS_BNH 1434880u   // 320 f32 shift
#define WS_WM1H 1436160u  // 4*64*32 f16 = 16384 B (Wm1 hi, B-frag order)
#define WS_WM1L 1452544u  // 16384 B (Wm1 lo)  -> end 1468928

__device__ inline f16x8 ld_frag_g(const _Float16* p) {
  union { uint4 u; f16x8 f; } c;
  c.u = *(const uint4*)p;
  return c.f;
}
__device__ inline f16x8 ld_frag_s(const _Float16* p) { return *(const f16x8*)p; }

// ---------------- prep (unchanged from R9) ----------------
__global__ __launch_bounds__(256) void prep_kernel(
    const float* __restrict__ W1, const float* __restrict__ W2,
    const float* __restrict__ b2, const float* __restrict__ Wr,
    const float* __restrict__ gamma, const float* __restrict__ beta,
    const float* __restrict__ rmean, const float* __restrict__ rvar,
    const float* __restrict__ Wm1, unsigned char* __restrict__ ws) {
  __shared__ __align__(16) float tile[32][68];
  const int tid = threadIdx.x;
  if (blockIdx.x < 330) {
    int l = blockIdx.x / 66, jb = blockIdx.x % 66;
    int s = tid >> 3, n0 = (tid & 7) * 8;
    int j = jb * 32 + s;
    const float* srcp = (j < 2048)
        ? (W2 + (size_t)l * 131072 + (size_t)j * 64 + n0)
        : (b2 + (size_t)l * 4096 + (size_t)(j - 2048) * 64 + n0);
    *(f32x4*)&tile[s][n0] = *(const f32x4*)srcp;
    *(f32x4*)&tile[s][n0 + 4] = *(const f32x4*)(srcp + 4);
    __syncthreads();
    int n = tid >> 2, sb = (tid & 3) * 8;
    f16x8 hv;
#pragma unroll
    for (int u = 0; u < 8; ++u) hv[u] = (_Float16)tile[sb + u][n];
    _Float16* dst = (_Float16*)(ws + WS_W2S) +
                    (size_t)l * 135168 + (size_t)jb * 2048 + n * 32 + sb;
    *(f16x8*)dst = hv;
    return;
  }
  int idx = (blockIdx.x - 330) * 256 + tid;
  _Float16* W1s = (_Float16*)(ws + WS_W1S);
  _Float16* Wrs = (_Float16*)(ws + WS_WRS);
  float* bns = (float*)(ws + WS_BNS);
  float* bnh = (float*)(ws + WS_BNH);
  _Float16* Wm1h = (_Float16*)(ws + WS_WM1H);
  _Float16* Wm1l = (_Float16*)(ws + WS_WM1L);
  if (idx < 20480) {            // W1s: K = 128
    int l = idx / 4096, r = idx % 4096;
    int t = r >> 10, n = (r >> 5) & 31, s2 = r & 31;
    int j = t * 32 + s2;
    W1s[idx] = (_Float16)W1[l * 4096 + j * 32 + n];
  } else if (idx < 40960) {     // Wrs: K = 64
    int i3 = idx - 20480;
    int l = i3 / 4096, r = i3 % 4096;
    int t = r >> 11, rem = r & 2047;
    int n = rem >> 5, s2 = rem & 31;
    int j = t * 32 + s2;
    Wrs[i3] = (_Float16)Wr[l * 4096 + j * 64 + n];
  } else if (idx < 41280) {     // BN folded
    int i4 = idx - 40960;
    float sc = gamma[i4] * rsqrtf(rvar[i4] + 1e-5f);
    bns[i4] = sc;
    bnh[i4] = beta[i4] - rmean[i4] * sc;
  } else if (idx < 49472) {     // Wm1 hi/lo: K = 128, N = 64
    int i5 = idx - 41280;
    int t = i5 >> 11, n = (i5 >> 5) & 63, s2 = i5 & 31;
    float w = Wm1[(t * 32 + s2) * 64 + n];
    _Float16 hi = (_Float16)w;
    Wm1h[i5] = hi;
    Wm1l[i5] = (_Float16)(w - (float)hi);
  }
}

// ---------------- main: one block per graph, 512 threads = 8 waves ----------------
__global__ __launch_bounds__(512, 4) void gnn_kernel(
    const float* __restrict__ x, const int* __restrict__ bu, const int* __restrict__ bv,
    const float* __restrict__ Wp, const float* __restrict__ bp,
    const float* __restrict__ b1, const float* __restrict__ brr,
    const float* __restrict__ bm1, const float* __restrict__ Wm2,
    const float* __restrict__ bm2,
    const _Float16* __restrict__ W2s, const _Float16* __restrict__ W1s,
    const _Float16* __restrict__ Wrs, const _Float16* __restrict__ Wm1h,
    const _Float16* __restrict__ Wm1l,
    const float* __restrict__ bns, const float* __restrict__ bnh,
    float* __restrict__ out) {
  __shared__ __align__(16) float hF[32][68];         // fp32 master h
  __shared__ __align__(16) _Float16 hH[32][72];      // f16 hi part of h
  __shared__ __align__(16) _Float16 hL[32][72];      // f16 lo part (h - hi)
  __shared__ __align__(16) _Float16 zEh[96][36];     // z edge-major [e][k], f16, pad 4
  __shared__ __align__(16) float agg[32][68];        // root*deg + msg accumulator
  __shared__ __align__(16) float hid2[64][48];       // head hidden [c][e]
  __shared__ int srcn[96], dstn[96];
  __shared__ float invdeg[32];
  __shared__ float degf[32];

  const int tid = threadIdx.x;
  const int g = blockIdx.x;
  const int wv = tid >> 6;     // 0..7
  const int ln = tid & 63;
  const int q = ln >> 4;
  const int m16 = ln & 15;
  const f32x4 zero4 = {0.f, 0.f, 0.f, 0.f};

  // ---- init: edge lists (both directions), pad rows (no agg init needed:
  // phase A plain-stores every agg row 0..31 each layer)
  if (tid < 96) {
    int s, d;
    if (tid < 41)      { s = bu[tid];      d = bv[tid]; }
    else if (tid < 82) { s = bv[tid - 41]; d = bu[tid - 41]; }
    else               { s = 0;            d = 0; }
    srcn[tid] = s; dstn[tid] = d;
  }
  if (tid < 136) { hF[30 + tid / 68][tid % 68] = 0.f; }
  if (tid < 144) {
    hH[30 + tid / 72][tid % 72] = (_Float16)0.f;
    hL[30 + tid / 72][tid % 72] = (_Float16)0.f;
  }
  __syncthreads();
  if (tid < 32) {
    int cnt = 0;
    for (int e = 0; e < 82; ++e) cnt += (dstn[e] == tid) ? 1 : 0;
    int c1 = (cnt > 0) ? cnt : 1;
    invdeg[tid] = 1.0f / (float)c1;
    degf[tid] = (float)c1;   // matches the invdeg clamp: (msg+root*deg)/deg
  }
  // ---- projection h0 = x @ Wp + bp (fp32, then split hi/lo); x rows as 2x float4
  for (int u = tid; u < 30 * 64; u += 512) {
    int n = u >> 6, c = u & 63;
    f32x4 xa = *(const f32x4*)&x[(g * 30 + n) * 8];
    f32x4 xb = *(const f32x4*)&x[(g * 30 + n) * 8 + 4];
    float acc = bp[c];
#pragma unroll
    for (int k = 0; k < 4; ++k) acc += xa[k] * Wp[k * 64 + c];
#pragma unroll
    for (int k = 0; k < 4; ++k) acc += xb[k] * Wp[(k + 4) * 64 + c];
    hF[n][c] = acc;
    _Float16 hi = (_Float16)acc;
    hH[n][c] = hi;
    hL[n][c] = (_Float16)(acc - (float)hi);
  }
  __syncthreads();   // also orders degf writes before phase-A reads

  for (int l = 0; l < 5; ++l) {
    // ======== phase A (balanced 16 MFMA/wave) ========
    // waves 0..5: two z-tiles each; waves 6..7: all 8 root tiles -> agg.
    if (wv < 6) {
      // z = relu([h_src|h_dst] @ W1 + b1) -> zEh[e][k] (f16)
      int ntz = (wv >= 3) ? 1 : 0;
      int mtb = (wv % 3) * 2;
      int ncol = ntz * 16 + m16;
      f16x8 bf[4];
#pragma unroll
      for (int t = 0; t < 4; ++t)
        bf[t] = ld_frag_g(W1s + ((l * 4 + t) * 32 + ncol) * 32 + q * 8);
      float b1v = b1[l * 32 + ncol];
#pragma unroll
      for (int mi = 0; mi < 2; ++mi) {
        int mt = mtb + mi;
        int e = mt * 16 + m16;
        int sn = srcn[e], dn = dstn[e];
        f32x4 acc = zero4;
#pragma unroll
        for (int t = 0; t < 4; ++t) {
          int nd = (t < 2) ? sn : dn;
          acc = MFMA16(ld_frag_s(&hH[nd][(t & 1) * 32 + q * 8]), bf[t], acc);
        }
#pragma unroll
        for (int t = 0; t < 4; ++t) {
          int nd = (t < 2) ? sn : dn;
          acc = MFMA16(ld_frag_s(&hL[nd][(t & 1) * 32 + q * 8]), bf[t], acc);
        }
#pragma unroll
        for (int r = 0; r < 4; ++r) {
          int e2 = mt * 16 + q * 4 + r;
          zEh[e2][ncol] = (_Float16)fmaxf(acc[r] + b1v, 0.f);  // pads never scattered
        }
      }
    } else {
      // root-GEMM: agg[row][col] = (h @ Wr)[row][col] * deg[row] (plain store)
#pragma unroll
      for (int nq = 0; nq < 2; ++nq) {
        int ncolR = ((wv - 6) * 2 + nq) * 16 + m16;
        f16x8 wb0 = ld_frag_g(Wrs + ((l * 2 + 0) * 64 + ncolR) * 32 + q * 8);
        f16x8 wb1 = ld_frag_g(Wrs + ((l * 2 + 1) * 64 + ncolR) * 32 + q * 8);
#pragma unroll
        for (int mtR = 0; mtR < 2; ++mtR) {
          f32x4 racc = zero4;
          racc = MFMA16(ld_frag_s(&hH[mtR * 16 + m16][q * 8]), wb0, racc);
          racc = MFMA16(ld_frag_s(&hH[mtR * 16 + m16][32 + q * 8]), wb1, racc);
          racc = MFMA16(ld_frag_s(&hL[mtR * 16 + m16][q * 8]), wb0, racc);
          racc = MFMA16(ld_frag_s(&hL[mtR * 16 + m16][32 + q * 8]), wb1, racc);
#pragma unroll
          for (int r = 0; r < 4; ++r) {
            int row = mtR * 16 + q * 4 + r;
            agg[row][ncolR] = racc[r] * degf[row & 31];
          }
        }
      }
    }
    __syncthreads();

    // ======== phase B: msg GEMM [96 x 2112] x [2112 x 64] ========
    {
      int nt = wv & 3, mh = wv >> 2;
      int e0 = mh * 48 + m16, e1 = e0 + 16, e2 = e0 + 32;
      f16x8 hA[3][2];
      {
        int s0 = srcn[e0], s1 = srcn[e1], s2 = srcn[e2];
        hA[0][0] = ld_frag_s(&hH[s0][q * 8]); hA[0][1] = ld_frag_s(&hH[s0][32 + q * 8]);
        hA[1][0] = ld_frag_s(&hH[s1][q * 8]); hA[1][1] = ld_frag_s(&hH[s1][32 + q * 8]);
        hA[2][0] = ld_frag_s(&hH[s2][q * 8]); hA[2][1] = ld_frag_s(&hH[s2][32 + q * 8]);
      }
      f32x4 macc[3] = {zero4, zero4, zero4};
      const _Float16* Wb = W2s + (size_t)l * 135168 + (nt * 16 + m16) * 32 + q * 8;
      // Bz first: bias MFMAs consume these before the ring drains.
      f16x8 Bz0 = ld_frag_g(Wb + (size_t)64 * 2048), Bz1 = ld_frag_g(Wb + (size_t)65 * 2048);
      f16x8 r0a = ld_frag_g(Wb + (size_t)0 * 2048), r0b = ld_frag_g(Wb + (size_t)1 * 2048);
      f16x8 r1a = ld_frag_g(Wb + (size_t)2 * 2048), r1b = ld_frag_g(Wb + (size_t)3 * 2048);
      f16x8 r2a = ld_frag_g(Wb + (size_t)4 * 2048), r2b = ld_frag_g(Wb + (size_t)5 * 2048);
      f16x8 r3a, r3b;
      macc[0] = MFMA16(hA[0][0], Bz0, macc[0]); macc[0] = MFMA16(hA[0][1], Bz1, macc[0]);
      macc[1] = MFMA16(hA[1][0], Bz0, macc[1]); macc[1] = MFMA16(hA[1][1], Bz1, macc[1]);
      macc[2] = MFMA16(hA[2][0], Bz0, macc[2]); macc[2] = MFMA16(hA[2][1], Bz1, macc[2]);
      // z group 0 preload (f16x4 = ds_read_b64)
      f16x4 zc0 = *(const f16x4*)&zEh[e0][0];
      f16x4 zc1 = *(const f16x4*)&zEh[e1][0];
      f16x4 zc2 = *(const f16x4*)&zEh[e2][0];
      for (int cb = 0; cb < 32; cb += 4) {
        f16x4 zb0 = zc0, zb1 = zc1, zb2 = zc2;
        zc0 = *(const f16x4*)&zEh[e0][cb + 4];   // next-group prefetch (pad-safe)
        zc1 = *(const f16x4*)&zEh[e1][cb + 4];
        zc2 = *(const f16x4*)&zEh[e2][cb + 4];
        // unconditional ring prefetch; overread (past layer end at l=4)
        // stays inside ws (< 1468928 B) and is never consumed.
        { // p=0: use slot0 (cb), prefetch cb+3 -> slot3
          r3a = ld_frag_g(Wb + (size_t)(2 * cb + 6) * 2048);
          r3b = ld_frag_g(Wb + (size_t)(2 * cb + 7) * 2048);
          _Float16 z0 = zb0[0], z1 = zb1[0], z2 = zb2[0];
          macc[0] = MFMA16(hA[0][0] * z0, r0a, macc[0]); macc[0] = MFMA16(hA[0][1] * z0, r0b, macc[0]);
          macc[1] = MFMA16(hA[1][0] * z1, r0a, macc[1]); macc[1] = MFMA16(hA[1][1] * z1, r0b, macc[1]);
          macc[2] = MFMA16(hA[2][0] * z2, r0a, macc[2]); macc[2] = MFMA16(hA[2][1] * z2, r0b, macc[2]);
        }
        { // p=1: use slot1 (cb+1), prefetch cb+4 -> slot0
          r0a = ld_frag_g(Wb + (size_t)(2 * cb + 8) * 2048);
          r0b = ld_frag_g(Wb + (size_t)(2 * cb + 9) * 2048);
          _Float16 z0 = zb0[1], z1 = zb1[1], z2 = zb2[1];
          macc[0] = MFMA16(hA[0][0] * z0, r1a, macc[0]); macc[0] = MFMA16(hA[0][1] * z0, r1b, macc[0]);
          macc[1] = MFMA16(hA[1][0] * z1, r1a, macc[1]); macc[1] = MFMA16(hA[1][1] * z1, r1b, macc[1]);
          macc[2] = MFMA16(hA[2][0] * z2, r1a, macc[2]); macc[2] = MFMA16(hA[2][1] * z2, r1b, macc[2]);
        }
        { // p=2: use slot2 (cb+2), prefetch cb+5 -> slot1
          r1a = ld_frag_g(Wb + (size_t)(2 * cb + 10) * 2048);
          r1b = ld_frag_g(Wb + (size_t)(2 * cb + 11) * 2048);
          _Float16 z0 = zb0[2], z1 = zb1[2], z2 = zb2[2];
          macc[0] = MFMA16(hA[0][0] * z0, r2a, macc[0]); macc[0] = MFMA16(hA[0][1] * z0, r2b, macc[0]);
          macc[1] = MFMA16(hA[1][0] * z1, r2a, macc[1]); macc[1] = MFMA16(hA[1][1] * z1, r2b, macc[1]);
          macc[2] = MFMA16(hA[2][0] * z2, r2a, macc[2]); macc[2] = MFMA16(hA[2][1] * z2, r2b, macc[2]);
        }
        { // p=3: use slot3 (cb+3), prefetch cb+6 -> slot2
          r2a = ld_frag_g(Wb + (size_t)(2 * cb + 12) * 2048);
          r2b = ld_frag_g(Wb + (size_t)(2 * cb + 13) * 2048);
          _Float16 z0 = zb0[3], z1 = zb1[3], z2 = zb2[3];
          macc[0] = MFMA16(hA[0][0] * z0, r3a, macc[0]); macc[0] = MFMA16(hA[0][1] * z0, r3b, macc[0]);
          macc[1] = MFMA16(hA[1][0] * z1, r3a, macc[1]); macc[1] = MFMA16(hA[1][1] * z1, r3b, macc[1]);
          macc[2] = MFMA16(hA[2][0] * z2, r3a, macc[2]); macc[2] = MFMA16(hA[2][1] * z2, r3b, macc[2]);
        }
      }
      // guarded scatter (pad edges e>=82 discarded)
#pragma unroll
      for (int mi = 0; mi < 3; ++mi) {
#pragma unroll
        for (int r = 0; r < 4; ++r) {
          int e = mh * 48 + mi * 16 + q * 4 + r;
          if (e < 82) atomicAdd(&agg[dstn[e]][nt * 16 + m16], macc[mi][r]);
        }
      }
    }
    __syncthreads();

    // ======== phase C: h = relu(BN(agg*invdeg + br)) + h (root inside agg) ========
    {
      const int ncolC = (wv & 3) * 16 + m16;
      const int mtC = wv >> 2;
      float scl = bns[l * 64 + ncolC];
      float sft = bnh[l * 64 + ncolC];
      float brb = brr[l * 64 + ncolC];
#pragma unroll
      for (int r = 0; r < 4; ++r) {
        int row = mtC * 16 + q * 4 + r;
        if (row < 30) {
          float v = agg[row][ncolC] * invdeg[row] + brb;
          v = v * scl + sft;
          float hn = fmaxf(v, 0.f) + hF[row][ncolC];
          hF[row][ncolC] = hn;
          _Float16 hi = (_Float16)hn;
          hH[row][ncolC] = hi;
          hL[row][ncolC] = (_Float16)(hn - (float)hi);
        }
      }
    }
    __syncthreads();
  }

  // ---- head: hid = relu([h_u|h_v] @ Wm1 + bm1) via MFMA (hi/lo x hi/lo, 3-term)
  {
    int nt = wv & 3, mtb = wv >> 2;
    int c = nt * 16 + m16;
    float bm1v = bm1[c];
    int nmt = (mtb == 0) ? 2 : 1;  // waves 0..3: mt {0,2}; waves 4..7: mt {1}
    for (int p2 = 0; p2 < nmt; ++p2) {
      int mt = (p2 == 0) ? mtb : 2;
      int e = mt * 16 + m16;       // rows 41..47 computed but discarded at stage 2
      int un = srcn[e], vn = dstn[e];
      f32x4 acc = zero4;
#pragma unroll
      for (int t = 0; t < 4; ++t) {
        int nd = (t < 2) ? un : vn;
        int co = (t & 1) * 32 + q * 8;
        f16x8 bh2 = ld_frag_g(Wm1h + (t * 64 + c) * 32 + q * 8);
        f16x8 bl2 = ld_frag_g(Wm1l + (t * 64 + c) * 32 + q * 8);
        f16x8 ah = ld_frag_s(&hH[nd][co]);
        f16x8 al = ld_frag_s(&hL[nd][co]);
        acc = MFMA16(ah, bh2, acc);
        acc = MFMA16(al, bh2, acc);
        acc = MFMA16(ah, bl2, acc);  // lo x lo dropped (~1e-6 rel)
      }
      f32x4 res;
#pragma unroll
      for (int r = 0; r < 4; ++r) res[r] = fmaxf(acc[r] + bm1v, 0.f);
      *(f32x4*)&hid2[c][mt * 16 + (q << 2)] = res;
    }
  }
  __syncthreads();
  if (tid < 41) {
    float acc = bm2[0];
#pragma unroll 4
    for (int c = 0; c < 64; ++c) acc += hid2[c][tid] * Wm2[c];
    out[g * 41 + tid] = acc;
  }
}

extern "C" void kernel_launch(void* const* d_in, const int* in_sizes, int n_in,
                              void* d_out, int out_size, void* d_ws, size_t ws_size,
                              hipStream_t stream) {
  const float* x   = (const float*)d_in[0];
  // d_in[1] = edge_index (rebuilt from branch lists), d_in[4] = num_graphs (const 512)
  const int* bu    = (const int*)d_in[2];
  const int* bv    = (const int*)d_in[3];
  const float* Wp  = (const float*)d_in[5];
  const float* bp  = (const float*)d_in[6];
  const float* W1  = (const float*)d_in[7];
  const float* b1  = (const float*)d_in[8];
  const float* W2  = (const float*)d_in[9];
  const float* b2  = (const float*)d_in[10];
  const float* Wr  = (const float*)d_in[11];
  const float* br  = (const float*)d_in[12];
  const float* gm  = (const float*)d_in[13];
  const float* bt  = (const float*)d_in[14];
  const float* rm  = (const float*)d_in[15];
  const float* rv  = (const float*)d_in[16];
  const float* Wm1 = (const float*)d_in[17];
  const float* bm1 = (const float*)d_in[18];
  const float* Wm2 = (const float*)d_in[19];
  const float* bm2 = (const float*)d_in[20];
  unsigned char* ws = (unsigned char*)d_ws;
  float* out = (float*)d_out;

  prep_kernel<<<524, 256, 0, stream>>>(W1, W2, b2, Wr, gm, bt, rm, rv, Wm1, ws);
  gnn_kernel<<<512, 512, 0, stream>>>(
      x, bu, bv, Wp, bp, b1, br, bm1, Wm2, bm2,
      (const _Float16*)(ws + WS_W2S),
      (const _Float16*)(ws + WS_W1S),
      (const _Float16*)(ws + WS_WRS),
      (const _Float16*)(ws + WS_WM1H),
      (const _Float16*)(ws + WS_WM1L),
      (const float*)(ws + WS_BNS),
      (const float*)(ws + WS_BNH),
      out);
}